// Round 1
// baseline (137.406 us; speedup 1.0000x reference)
//
#include <hip/hip_runtime.h>

#define NA 2048
#define CDIM 8
#define CONVF 332.07156f

// ---------------- precompute: per-atom factors + E_solv ----------------
__global__ __launch_bounds__(256) void precompute_kernel(
    const float* __restrict__ X,
    const float* __restrict__ embs,
    const float* __restrict__ qs,
    const float* __restrict__ Ps,
    const float* __restrict__ w0,
    const float* __restrict__ s0,
    const float* __restrict__ sf_elec,
    const float* __restrict__ born,
    const float* __restrict__ die,
    const float* __restrict__ depth,
    const float* __restrict__ radius,
    float4* __restrict__ pk0,   // x, y, z, q
    float4* __restrict__ pk1,   // sfA, rfA, dfA, s0
    float4* __restrict__ pk2,   // w0j, Psx, Psy, Psz
    float4* __restrict__ isd,   // sfB, rfB, dfB, 0   (i-side)
    float* __restrict__ d_out)
{
    int i = blockIdx.x * blockDim.x + threadIdx.x;
    float e_self = 0.0f;
    if (i < NA) {
        float e[CDIM];
#pragma unroll
        for (int k = 0; k < CDIM; ++k) e[k] = embs[i * CDIM + k];
        float sfA = 0.f, sfB = 0.f, rfA = 0.f, rfB = 0.f, dfA = 0.f, dfB = 0.f;
        float dieV = 0.f, Rv = 0.f;
#pragma unroll
        for (int k = 0; k < CDIM; ++k) {
            sfA  += e[k] * sf_elec[k];
            sfB  += e[k] * sf_elec[CDIM + k];
            rfA  += e[k] * radius[k];
            rfB  += e[k] * radius[CDIM + k];
            dfA  += e[k] * depth[k];
            dfB  += e[k] * depth[CDIM + k];
            dieV += e[k] * die[k];
            Rv   += e[k] * born[k];
        }
        dieV += 1e-6f;
        Rv += 1.0f;
        float q = qs[i];
        e_self = -(1.0f - 1.0f / dieV) * q / (Rv + 1e-6f);

        pk0[i] = make_float4(X[i * 3 + 0], X[i * 3 + 1], X[i * 3 + 2], q);
        pk1[i] = make_float4(sfA, rfA, dfA, s0[i]);
        float w0j = sqrtf(w0[i] * w0[i] + 1e-6f);
        pk2[i] = make_float4(w0j, Ps[i * 3 + 0], Ps[i * 3 + 1], Ps[i * 3 + 2]);
        isd[i] = make_float4(sfB, rfB, dfB, 0.0f);
    }
    // block reduce e_self (wave64 shuffle + LDS across 4 waves)
#pragma unroll
    for (int off = 32; off > 0; off >>= 1)
        e_self += __shfl_down(e_self, off);
    __shared__ float ss[4];
    int lane = threadIdx.x & 63, wid = threadIdx.x >> 6;
    if (lane == 0) ss[wid] = e_self;
    __syncthreads();
    if (threadIdx.x == 0) {
        float t = ss[0] + ss[1] + ss[2] + ss[3];
        atomicAdd(d_out + 2, CONVF * 0.01f * t);   // E_solv
    }
}

// ---------------- pair pass: one block per row i ----------------
__global__ __launch_bounds__(256) void pair_kernel(
    const float4* __restrict__ pk0,
    const float4* __restrict__ pk1,
    const float4* __restrict__ pk2,
    const float4* __restrict__ isd,
    const int* __restrict__ chain,
    const float* __restrict__ sf_elec,
    float* __restrict__ d_out)
{
    const int i = blockIdx.x;
    const int tid = threadIdx.x;
    const float f16 = sf_elec[2 * CDIM];

    const float4 p0i = pk0[i];
    const float4 p2i = pk2[i];
    const float4 isi = isd[i];
    const float xi = p0i.x, yi = p0i.y, zi = p0i.z, qi = p0i.w;
    const float sfB = isi.x, rfB = isi.y, dfB = isi.z;
    const float psx = p2i.y, psy = p2i.z, psz = p2i.w;
    const int ci = chain[i];

    float acc_e = 0.0f, acc_v = 0.0f;

#pragma unroll 2
    for (int j = tid; j < NA; j += 256) {
        const float4 a = pk0[j];
        const float4 b = pk1[j];
        const float4 c = pk2[j];
        const float m = (chain[j] != ci) ? 1.0f : 0.0f;

        // V[i,j] = X[j] - X[i]
        const float dx = a.x - xi, dy = a.y - yi, dz = a.z - zi;
        const float d2 = dx * dx + dy * dy + dz * dz + 3e-6f; // sum(V*V + 1e-6)
        const float D = sqrtf(d2);
        const float invD = 1.0f / (D + 1e-6f);

        // Vn . Ps_i  and Ps_i . Ps_j
        const float vpx = dx + 1e-6f, vpy = dy + 1e-6f, vpz = dz + 1e-6f;
        const float vnorm = fmaxf(sqrtf(vpx * vpx + vpy * vpy + vpz * vpz), 1e-12f);
        const float OqP = (vpx * psx + vpy * psy + vpz * psz) / vnorm;
        const float OPP = psx * c.y + psy * c.z + psz * c.w;

        const float sf = b.x + sfB + invD * f16;
        const float invD2 = invD * invD;
        const float invD3 = invD2 * invD;
        const float invD4 = invD2 * invD2;
        const float invD6 = invD3 * invD3;
        const float eqq = qi * a.w * invD * sf;
        acc_e += m * (eqq + OqP * invD4 + OPP * invD6);

        // vdw
        const float sig_r = 1.0f / (1.0f + __expf(-(b.y + rfB)));
        const float s = 2.0f * b.w * (0.8f * sig_r + 0.4f);
        const float repl = 5.0f * __expf(-0.3f * D * d2);   // D^3 = D * d2
        const float Dm = D - s;
        const float dm1 = Dm - 0.3f;
        const float attr = (__expf(-dm1 * dm1) + __expf(-3.0f * Dm * Dm) +
                            __expf(-10.0f * Dm * Dm)) * (1.0f / 3.0f);
        const float sig_d = 1.0f / (1.0f + __expf(-(b.z + dfB)));
        const float w = c.x * (sig_d + 0.5f);
        acc_v += m * (-w * attr + repl);
    }

    // block reduce (wave64 shuffle + LDS across 4 waves)
#pragma unroll
    for (int off = 32; off > 0; off >>= 1) {
        acc_e += __shfl_down(acc_e, off);
        acc_v += __shfl_down(acc_v, off);
    }
    __shared__ float se[4], sv[4];
    int lane = tid & 63, wid = tid >> 6;
    if (lane == 0) { se[wid] = acc_e; sv[wid] = acc_v; }
    __syncthreads();
    if (tid == 0) {
        float te = se[0] + se[1] + se[2] + se[3];
        float tv = sv[0] + sv[1] + sv[2] + sv[3];
        atomicAdd(d_out + 1, 0.5f * CONVF * te);  // E_elec
        atomicAdd(d_out + 0, tv);                 // E_vdw
    }
}

extern "C" void kernel_launch(void* const* d_in, const int* in_sizes, int n_in,
                              void* d_out, int out_size, void* d_ws, size_t ws_size,
                              hipStream_t stream) {
    const float* X       = (const float*)d_in[0];
    const float* embs    = (const float*)d_in[1];
    const float* qs      = (const float*)d_in[2];
    const float* Ps      = (const float*)d_in[3];
    const float* w0      = (const float*)d_in[4];
    const float* s0      = (const float*)d_in[5];
    const int*   chain   = (const int*)d_in[6];
    const float* sf_elec = (const float*)d_in[7];
    const float* born    = (const float*)d_in[8];
    const float* die     = (const float*)d_in[9];
    const float* depth   = (const float*)d_in[10];
    const float* radius  = (const float*)d_in[11];
    float* out = (float*)d_out;

    float4* pk0 = (float4*)d_ws;
    float4* pk1 = pk0 + NA;
    float4* pk2 = pk1 + NA;
    float4* isd = pk2 + NA;

    hipMemsetAsync(d_out, 0, 3 * sizeof(float), stream);
    precompute_kernel<<<NA / 256, 256, 0, stream>>>(
        X, embs, qs, Ps, w0, s0, sf_elec, born, die, depth, radius,
        pk0, pk1, pk2, isd, out);
    pair_kernel<<<NA, 256, 0, stream>>>(pk0, pk1, pk2, isd, chain, sf_elec, out);
}

// Round 2
// 102.136 us; speedup vs baseline: 1.3453x; 1.3453x over previous
//
#include <hip/hip_runtime.h>

#define NA 2048
#define CDIM 8
#define CONVF 332.07156f
#define TI 4            // i-rows per block in pair pass
#define PAIR_GRID 516   // >= max ceil(n0/TI)+ceil(n1/TI) = 513

// ws layout: [0..15] int counters {n0, p0, p1, pad}; then 8 float4 arrays of NA
// u0..u3 unsorted, g0..g3 sorted-by-chain.

// ---------------- precompute: per-atom factors, chain count, E_solv --------
__global__ __launch_bounds__(256) void precompute_kernel(
    const float* __restrict__ X,
    const float* __restrict__ embs,
    const float* __restrict__ qs,
    const float* __restrict__ Ps,
    const float* __restrict__ w0,
    const float* __restrict__ s0,
    const int* __restrict__ chain,
    const float* __restrict__ sf_elec,
    const float* __restrict__ born,
    const float* __restrict__ die,
    const float* __restrict__ depth,
    const float* __restrict__ radius,
    int* __restrict__ cnt,
    float4* __restrict__ u0, float4* __restrict__ u1,
    float4* __restrict__ u2, float4* __restrict__ u3,
    float* __restrict__ d_out)
{
    int i = blockIdx.x * 256 + threadIdx.x;
    float e_self = 0.0f;
    int c0 = 0;
    {
        float e[CDIM];
#pragma unroll
        for (int k = 0; k < CDIM; ++k) e[k] = embs[i * CDIM + k];
        float sfA = 0.f, sfB = 0.f, rfA = 0.f, rfB = 0.f, dfA = 0.f, dfB = 0.f;
        float dieV = 0.f, Rv = 0.f;
#pragma unroll
        for (int k = 0; k < CDIM; ++k) {
            sfA  += e[k] * sf_elec[k];
            sfB  += e[k] * sf_elec[CDIM + k];
            rfA  += e[k] * radius[k];
            rfB  += e[k] * radius[CDIM + k];
            dfA  += e[k] * depth[k];
            dfB  += e[k] * depth[CDIM + k];
            dieV += e[k] * die[k];
            Rv   += e[k] * born[k];
        }
        dieV += 1e-6f;
        Rv += 1.0f;
        float q = qs[i];
        e_self = -(1.0f - 1.0f / dieV) * q / (Rv + 1e-6f);

        float erA = __expf(-rfA), edA = __expf(-dfA);
        float erB = __expf(-rfB), edB = __expf(-dfB);
        float w0j = sqrtf(w0[i] * w0[i] + 1e-6f);

        u0[i] = make_float4(X[i * 3 + 0], X[i * 3 + 1], X[i * 3 + 2], q);
        u1[i] = make_float4(sfA, erA, edA, w0j);
        u2[i] = make_float4(2.0f * s0[i], Ps[i * 3 + 0], Ps[i * 3 + 1], Ps[i * 3 + 2]);
        u3[i] = make_float4(sfB, erB, edB, 0.0f);
        c0 = (chain[i] == 0) ? 1 : 0;
    }
#pragma unroll
    for (int off = 32; off > 0; off >>= 1) {
        e_self += __shfl_down(e_self, off);
        c0     += __shfl_down(c0, off);
    }
    __shared__ float ss[4];
    __shared__ int sc[4];
    int lane = threadIdx.x & 63, wid = threadIdx.x >> 6;
    if (lane == 0) { ss[wid] = e_self; sc[wid] = c0; }
    __syncthreads();
    if (threadIdx.x == 0) {
        atomicAdd(d_out + 2, CONVF * 0.01f * (ss[0] + ss[1] + ss[2] + ss[3]));
        atomicAdd(cnt + 0, sc[0] + sc[1] + sc[2] + sc[3]);
    }
}

// ---------------- scatter: chain0 atoms to [0,n0), chain1 to [n0,NA) -------
__global__ __launch_bounds__(256) void scatter_kernel(
    const int* __restrict__ chain, int* __restrict__ cnt,
    const float4* __restrict__ u0, const float4* __restrict__ u1,
    const float4* __restrict__ u2, const float4* __restrict__ u3,
    float4* __restrict__ g0, float4* __restrict__ g1,
    float4* __restrict__ g2, float4* __restrict__ g3)
{
    int i = blockIdx.x * 256 + threadIdx.x;
    int n0 = cnt[0];
    int slot = (chain[i] == 0) ? atomicAdd(cnt + 1, 1)
                               : n0 + atomicAdd(cnt + 2, 1);
    g0[slot] = u0[i];
    g1[slot] = u1[i];
    g2[slot] = u2[i];
    g3[slot] = u3[i];
}

// ---------------- pair pass: TI rows per block over opposite-chain region --
__global__ __launch_bounds__(256) void pair_kernel(
    const int* __restrict__ cnt,
    const float4* __restrict__ g0, const float4* __restrict__ g1,
    const float4* __restrict__ g2, const float4* __restrict__ g3,
    const float* __restrict__ sf_elec,
    float* __restrict__ d_out)
{
    const int b = blockIdx.x, tid = threadIdx.x;
    const int n0 = cnt[0];
    const int B0 = (n0 + TI - 1) / TI;
    const int n1 = NA - n0;
    const int B1 = (n1 + TI - 1) / TI;
    if (b >= B0 + B1) return;

    int rbase, rend, jbeg, jend;
    if (b < B0) { rbase = b * TI;             rend = n0; jbeg = n0; jend = NA; }
    else        { rbase = n0 + (b - B0) * TI; rend = NA; jbeg = 0;  jend = n0; }

    const float f16 = sf_elec[2 * CDIM];

    float xi[TI], yi[TI], zi[TI], qi[TI], sfB[TI], erB[TI], edB[TI], val[TI];
    float psx[TI], psy[TI], psz[TI];
    bool hasPs = false;
#pragma unroll
    for (int t = 0; t < TI; ++t) {
        int r = rbase + t;
        val[t] = (r < rend) ? 1.0f : 0.0f;
        r = min(r, rend - 1);
        float4 p0 = g0[r], p3 = g3[r], p2 = g2[r];
        xi[t] = p0.x; yi[t] = p0.y; zi[t] = p0.z; qi[t] = p0.w;
        sfB[t] = p3.x; erB[t] = p3.y; edB[t] = p3.z;
        psx[t] = p2.y; psy[t] = p2.z; psz[t] = p2.w;
        hasPs = hasPs || (psx[t] != 0.0f) || (psy[t] != 0.0f) || (psz[t] != 0.0f);
    }

    float acc_e[TI], acc_v[TI];
#pragma unroll
    for (int t = 0; t < TI; ++t) { acc_e[t] = 0.f; acc_v[t] = 0.f; }

    const float* g2f = (const float*)g2;

#pragma unroll 2
    for (int j = jbeg + tid; j < jend; j += 256) {
        const float4 a = g0[j];
        const float4 bb = g1[j];
        float s0x2, pjx = 0.f, pjy = 0.f, pjz = 0.f;
        if (hasPs) {
            float4 c2 = g2[j];
            s0x2 = c2.x; pjx = c2.y; pjy = c2.z; pjz = c2.w;
        } else {
            s0x2 = g2f[4 * j];
        }

#pragma unroll
        for (int t = 0; t < TI; ++t) {
            const float dx = a.x - xi[t], dy = a.y - yi[t], dz = a.z - zi[t];
            const float d2 = dx * dx + dy * dy + dz * dz + 3e-6f;
            const float D = sqrtf(d2);
            const float invD = __builtin_amdgcn_rcpf(D + 1e-6f);

            // elec
            const float sf = bb.x + sfB[t] + invD * f16;
            float ee = qi[t] * a.w * invD * sf;
            if (hasPs) {
                const float vpx = dx + 1e-6f, vpy = dy + 1e-6f, vpz = dz + 1e-6f;
                float vn = sqrtf(vpx * vpx + vpy * vpy + vpz * vpz);
                vn = fmaxf(vn, 1e-12f);
                const float OqP = (vpx * psx[t] + vpy * psy[t] + vpz * psz[t]) *
                                  __builtin_amdgcn_rcpf(vn);
                const float OPP = psx[t] * pjx + psy[t] * pjy + psz[t] * pjz;
                const float invD2 = invD * invD;
                const float invD4 = invD2 * invD2;
                const float invD6 = invD4 * invD2;
                ee += OqP * invD4 + OPP * invD6;
            }
            acc_e[t] += ee;

            // vdw: sigmoids via precomputed exps (separable)
            const float sig_r = __builtin_amdgcn_rcpf(fmaf(bb.y, erB[t], 1.0f));
            const float s = s0x2 * fmaf(0.8f, sig_r, 0.4f);
            const float Dm = D - s;
            const float Dm2 = Dm * Dm;
            const float t1 = __expf(-Dm2);
            const float ta = t1 * __expf(fmaf(0.6f, Dm, -0.09f));
            const float t2 = t1 * t1;
            const float t3 = t2 * t1;
            const float t4 = t2 * t2;
            const float t8 = t4 * t4;
            const float t10 = t8 * t2;
            const float attr = ta + t3 + t10;
            const float sig_d = __builtin_amdgcn_rcpf(fmaf(bb.z, edB[t], 1.0f));
            const float w = bb.w * (sig_d + 0.5f);
            const float repl = 5.0f * __expf(-0.3f * D * d2);
            acc_v[t] += repl - w * attr * (1.0f / 3.0f);
        }
    }

    float ae = 0.f, av = 0.f;
#pragma unroll
    for (int t = 0; t < TI; ++t) {
        ae += val[t] * acc_e[t];
        av += val[t] * acc_v[t];
    }
#pragma unroll
    for (int off = 32; off > 0; off >>= 1) {
        ae += __shfl_down(ae, off);
        av += __shfl_down(av, off);
    }
    __shared__ float se[4], sv[4];
    int lane = tid & 63, wid = tid >> 6;
    if (lane == 0) { se[wid] = ae; sv[wid] = av; }
    __syncthreads();
    if (tid == 0) {
        atomicAdd(d_out + 1, 0.5f * CONVF * (se[0] + se[1] + se[2] + se[3]));
        atomicAdd(d_out + 0, sv[0] + sv[1] + sv[2] + sv[3]);
    }
}

extern "C" void kernel_launch(void* const* d_in, const int* in_sizes, int n_in,
                              void* d_out, int out_size, void* d_ws, size_t ws_size,
                              hipStream_t stream) {
    const float* X       = (const float*)d_in[0];
    const float* embs    = (const float*)d_in[1];
    const float* qs      = (const float*)d_in[2];
    const float* Ps      = (const float*)d_in[3];
    const float* w0      = (const float*)d_in[4];
    const float* s0      = (const float*)d_in[5];
    const int*   chain   = (const int*)d_in[6];
    const float* sf_elec = (const float*)d_in[7];
    const float* born    = (const float*)d_in[8];
    const float* die     = (const float*)d_in[9];
    const float* depth   = (const float*)d_in[10];
    const float* radius  = (const float*)d_in[11];
    float* out = (float*)d_out;

    int* cnt = (int*)d_ws;
    float4* u0 = (float4*)((char*)d_ws + 16);
    float4* u1 = u0 + NA;
    float4* u2 = u1 + NA;
    float4* u3 = u2 + NA;
    float4* g0 = u3 + NA;
    float4* g1 = g0 + NA;
    float4* g2 = g1 + NA;
    float4* g3 = g2 + NA;

    hipMemsetAsync(d_out, 0, 3 * sizeof(float), stream);
    hipMemsetAsync(d_ws, 0, 16, stream);
    precompute_kernel<<<NA / 256, 256, 0, stream>>>(
        X, embs, qs, Ps, w0, s0, chain, sf_elec, born, die, depth, radius,
        cnt, u0, u1, u2, u3, out);
    scatter_kernel<<<NA / 256, 256, 0, stream>>>(chain, cnt, u0, u1, u2, u3,
                                                 g0, g1, g2, g3);
    pair_kernel<<<PAIR_GRID, 256, 0, stream>>>(cnt, g0, g1, g2, g3, sf_elec, out);
}

// Round 6
// 97.523 us; speedup vs baseline: 1.4090x; 1.0473x over previous
//
#include <hip/hip_runtime.h>

#define NA 2048
#define CDIM 8
#define CONVF 332.07156f
#define TI 4            // i-rows per block in pair pass
#define PAIR_GRID 516   // >= ceil(n0/TI)+ceil(n1/TI) (max 514); extras early-exit

// ws layout (bytes):
//   [0..3]   int  wsi[0] : n0 (count of chain-0 atoms)
//   [128..]  g0..g3 (each NA float4), sorted by chain

// ------- kernel 1: one block, precompute + deterministic chain-sort + solv ---
__global__ __launch_bounds__(1024) void pre_kernel(
    const float* __restrict__ X,
    const float* __restrict__ embs,
    const float* __restrict__ qs,
    const float* __restrict__ Ps,
    const float* __restrict__ w0,
    const float* __restrict__ s0,
    const int* __restrict__ chain,
    const float* __restrict__ sf_elec,
    const float* __restrict__ born,
    const float* __restrict__ die,
    const float* __restrict__ depth,
    const float* __restrict__ radius,
    int* __restrict__ wsi,
    float4* __restrict__ g0, float4* __restrict__ g1,
    float4* __restrict__ g2, float4* __restrict__ g3,
    float* __restrict__ d_out)
{
    const int t = threadIdx.x;          // 0..1023, atoms 2t and 2t+1
    const int i0 = 2 * t, i1 = 2 * t + 1;

    float4 a0[2], a1[2], a2[2], a3[2];
    int flag[2];
    float es = 0.0f;

#pragma unroll
    for (int h = 0; h < 2; ++h) {
        const int i = (h == 0) ? i0 : i1;
        float e[CDIM];
#pragma unroll
        for (int k = 0; k < CDIM; ++k) e[k] = embs[i * CDIM + k];
        float sfA = 0.f, sfB = 0.f, rfA = 0.f, rfB = 0.f, dfA = 0.f, dfB = 0.f;
        float dieV = 0.f, Rv = 0.f;
#pragma unroll
        for (int k = 0; k < CDIM; ++k) {
            sfA  += e[k] * sf_elec[k];
            sfB  += e[k] * sf_elec[CDIM + k];
            rfA  += e[k] * radius[k];
            rfB  += e[k] * radius[CDIM + k];
            dfA  += e[k] * depth[k];
            dfB  += e[k] * depth[CDIM + k];
            dieV += e[k] * die[k];
            Rv   += e[k] * born[k];
        }
        dieV += 1e-6f;
        Rv += 1.0f;
        const float q = qs[i];
        es += -(1.0f - 1.0f / dieV) * q / (Rv + 1e-6f);

        const float erB = __expf(-rfB), edB = __expf(-dfB);
        const float erA = __expf(-rfA), edA = __expf(-dfA);
        const float w0j = sqrtf(w0[i] * w0[i] + 1e-6f);

        a0[h] = make_float4(X[i * 3 + 0], X[i * 3 + 1], X[i * 3 + 2], q);
        a1[h] = make_float4(sfA, erA, edA, w0j);
        a2[h] = make_float4(2.0f * s0[i], Ps[i * 3 + 0], Ps[i * 3 + 1], Ps[i * 3 + 2]);
        a3[h] = make_float4(sfB, erB, edB, 0.0f);
        flag[h] = (chain[i] == 0) ? 1 : 0;
    }

    // ---- block-wide exclusive prefix over chain-0 flags (2 atoms/thread) ----
    const int lane = t & 63, wv = t >> 6;       // 16 waves
    int cnt = flag[0] + flag[1];
    int x = cnt;
#pragma unroll
    for (int off = 1; off < 64; off <<= 1) {
        int y = __shfl_up(x, off);
        if (lane >= off) x += y;
    }
    const int excl = x - cnt;                   // exclusive within wave

    __shared__ int wsum[16];
    __shared__ float fsum[16];
    if (lane == 63) wsum[wv] = x;               // wave-inclusive total
    // e_self wave reduce
    float esw = es;
#pragma unroll
    for (int off = 32; off > 0; off >>= 1) esw += __shfl_down(esw, off);
    if (lane == 0) fsum[wv] = esw;
    __syncthreads();

    int wbase = 0, tot = 0;
#pragma unroll
    for (int k = 0; k < 16; ++k) {
        int v = wsum[k];
        if (k < wv) wbase += v;
        tot += v;
    }
    const int base = wbase + excl;              // #chain0 atoms before atom i0

    // slots: chain0 -> prefix0 ; chain1 -> n0 + (i - prefix0)
    const int p0_0 = base;
    const int slot0 = flag[0] ? p0_0 : tot + (i0 - p0_0);
    const int p0_1 = base + flag[0];
    const int slot1 = flag[1] ? p0_1 : tot + (i1 - p0_1);

    g0[slot0] = a0[0]; g1[slot0] = a1[0]; g2[slot0] = a2[0]; g3[slot0] = a3[0];
    g0[slot1] = a0[1]; g1[slot1] = a1[1]; g2[slot1] = a2[1]; g3[slot1] = a3[1];

    if (t == 0) {
        float tt = 0.f;
#pragma unroll
        for (int k = 0; k < 16; ++k) tt += fsum[k];
        d_out[2] = CONVF * 0.01f * tt;          // E_solv
        d_out[0] = 0.0f;
        d_out[1] = 0.0f;
        wsi[0] = tot;                           // n0
    }
}

// ------- kernel 2: opposite-chain pair pass (validated in round 2) ----------
__global__ __launch_bounds__(256) void pair_kernel(
    const int* __restrict__ cnt,
    const float4* __restrict__ g0, const float4* __restrict__ g1,
    const float4* __restrict__ g2, const float4* __restrict__ g3,
    const float* __restrict__ sf_elec,
    float* __restrict__ d_out)
{
    const int b = blockIdx.x, tid = threadIdx.x;
    const int n0 = cnt[0];
    const int B0 = (n0 + TI - 1) / TI;
    const int n1 = NA - n0;
    const int B1 = (n1 + TI - 1) / TI;
    if (b >= B0 + B1) return;

    int rbase, rend, jbeg, jend;
    if (b < B0) { rbase = b * TI;             rend = n0; jbeg = n0; jend = NA; }
    else        { rbase = n0 + (b - B0) * TI; rend = NA; jbeg = 0;  jend = n0; }

    const float f16 = sf_elec[2 * CDIM];

    float xi[TI], yi[TI], zi[TI], qi[TI], sfB[TI], erB[TI], edB[TI], val[TI];
    float psx[TI], psy[TI], psz[TI];
    bool hasPs = false;
#pragma unroll
    for (int t = 0; t < TI; ++t) {
        int r = rbase + t;
        val[t] = (r < rend) ? 1.0f : 0.0f;
        r = min(r, rend - 1);
        r = max(r, 0);
        float4 p0 = g0[r], p3 = g3[r], p2 = g2[r];
        xi[t] = p0.x; yi[t] = p0.y; zi[t] = p0.z; qi[t] = p0.w;
        sfB[t] = p3.x; erB[t] = p3.y; edB[t] = p3.z;
        psx[t] = p2.y; psy[t] = p2.z; psz[t] = p2.w;
        hasPs = hasPs || (psx[t] != 0.0f) || (psy[t] != 0.0f) || (psz[t] != 0.0f);
    }

    float acc_e[TI], acc_v[TI];
#pragma unroll
    for (int t = 0; t < TI; ++t) { acc_e[t] = 0.f; acc_v[t] = 0.f; }

    const float* g2f = (const float*)g2;

#pragma unroll 2
    for (int j = jbeg + tid; j < jend; j += 256) {
        const float4 a = g0[j];
        const float4 bb = g1[j];
        float s0x2, pjx = 0.f, pjy = 0.f, pjz = 0.f;
        if (hasPs) {
            float4 c2 = g2[j];
            s0x2 = c2.x; pjx = c2.y; pjy = c2.z; pjz = c2.w;
        } else {
            s0x2 = g2f[4 * j];
        }

#pragma unroll
        for (int t = 0; t < TI; ++t) {
            const float dx = a.x - xi[t], dy = a.y - yi[t], dz = a.z - zi[t];
            const float d2 = dx * dx + dy * dy + dz * dz + 3e-6f;
            const float D = sqrtf(d2);
            const float invD = __builtin_amdgcn_rcpf(D + 1e-6f);

            // elec
            const float sf = bb.x + sfB[t] + invD * f16;
            float ee = qi[t] * a.w * invD * sf;
            if (hasPs) {
                const float vpx = dx + 1e-6f, vpy = dy + 1e-6f, vpz = dz + 1e-6f;
                float vn = sqrtf(vpx * vpx + vpy * vpy + vpz * vpz);
                vn = fmaxf(vn, 1e-12f);
                const float OqP = (vpx * psx[t] + vpy * psy[t] + vpz * psz[t]) *
                                  __builtin_amdgcn_rcpf(vn);
                const float OPP = psx[t] * pjx + psy[t] * pjy + psz[t] * pjz;
                const float invD2 = invD * invD;
                const float invD4 = invD2 * invD2;
                const float invD6 = invD4 * invD2;
                ee += OqP * invD4 + OPP * invD6;
            }
            acc_e[t] += ee;

            // vdw: sigmoids via precomputed separable exps
            const float sig_r = __builtin_amdgcn_rcpf(fmaf(bb.y, erB[t], 1.0f));
            const float s = s0x2 * fmaf(0.8f, sig_r, 0.4f);
            const float Dm = D - s;
            const float Dm2 = Dm * Dm;
            const float t1 = __expf(-Dm2);
            const float ta = t1 * __expf(fmaf(0.6f, Dm, -0.09f));
            const float t2 = t1 * t1;
            const float t3 = t2 * t1;
            const float t4 = t2 * t2;
            const float t8 = t4 * t4;
            const float t10 = t8 * t2;
            const float attr = ta + t3 + t10;
            const float sig_d = __builtin_amdgcn_rcpf(fmaf(bb.z, edB[t], 1.0f));
            const float w = bb.w * (sig_d + 0.5f);
            const float repl = 5.0f * __expf(-0.3f * D * d2);
            acc_v[t] += repl - w * attr * (1.0f / 3.0f);
        }
    }

    float ae = 0.f, av = 0.f;
#pragma unroll
    for (int t = 0; t < TI; ++t) {
        ae += val[t] * acc_e[t];
        av += val[t] * acc_v[t];
    }
#pragma unroll
    for (int off = 32; off > 0; off >>= 1) {
        ae += __shfl_down(ae, off);
        av += __shfl_down(av, off);
    }
    __shared__ float se[4], sv[4];
    const int lane = tid & 63, wid = tid >> 6;
    if (lane == 0) { se[wid] = ae; sv[wid] = av; }
    __syncthreads();
    if (tid == 0) {
        atomicAdd(d_out + 1, 0.5f * CONVF * (se[0] + se[1] + se[2] + se[3]));
        atomicAdd(d_out + 0, sv[0] + sv[1] + sv[2] + sv[3]);
    }
}

extern "C" void kernel_launch(void* const* d_in, const int* in_sizes, int n_in,
                              void* d_out, int out_size, void* d_ws, size_t ws_size,
                              hipStream_t stream) {
    const float* X       = (const float*)d_in[0];
    const float* embs    = (const float*)d_in[1];
    const float* qs      = (const float*)d_in[2];
    const float* Ps      = (const float*)d_in[3];
    const float* w0      = (const float*)d_in[4];
    const float* s0      = (const float*)d_in[5];
    const int*   chain   = (const int*)d_in[6];
    const float* sf_elec = (const float*)d_in[7];
    const float* born    = (const float*)d_in[8];
    const float* die     = (const float*)d_in[9];
    const float* depth   = (const float*)d_in[10];
    const float* radius  = (const float*)d_in[11];
    float* out = (float*)d_out;

    int* wsi = (int*)d_ws;
    float4* g0 = (float4*)((char*)d_ws + 128);
    float4* g1 = g0 + NA;
    float4* g2 = g1 + NA;
    float4* g3 = g2 + NA;

    pre_kernel<<<1, 1024, 0, stream>>>(
        X, embs, qs, Ps, w0, s0, chain, sf_elec, born, die, depth, radius,
        wsi, g0, g1, g2, g3, out);
    pair_kernel<<<PAIR_GRID, 256, 0, stream>>>(wsi, g0, g1, g2, g3, sf_elec, out);
}

// Round 8
// 93.108 us; speedup vs baseline: 1.4758x; 1.0474x over previous
//
#include <hip/hip_runtime.h>

#define NA 2048
#define CDIM 8
#define CONVF 332.07156f
#define PTI 8            // i-rows per block in pair pass
#define PTHREADS 512
#define CH 1024          // j-chunk staged in LDS
#define PAIR_GRID 258    // work blocks <= 257; block 257 = E_solv finalizer

// ws layout (bytes):
//   [0..3]    int   wsi[0]   : n0 (count of chain-0 atoms)
//   [64..95]  float wsf[0..7]: per-block E_self partials
//   [128..]   g0..g3 (each NA float4), sorted by chain

// ------- kernel 1: 9 blocks. 0..7: precompute + chain-sort scatter ----------
// each block redundantly computes the global prefix over chain-0 flags via an
// 8-flags-per-thread LDS scan (no cross-block communication). block 8 zeroes
// d_out[0..1].
__global__ __launch_bounds__(256) void pre_kernel(
    const float* __restrict__ X,
    const float* __restrict__ embs,
    const float* __restrict__ qs,
    const float* __restrict__ Ps,
    const float* __restrict__ w0,
    const float* __restrict__ s0,
    const int* __restrict__ chain,
    const float* __restrict__ sf_elec,
    const float* __restrict__ born,
    const float* __restrict__ die,
    const float* __restrict__ depth,
    const float* __restrict__ radius,
    int* __restrict__ wsi,
    float* __restrict__ wsf,
    float4* __restrict__ g0, float4* __restrict__ g1,
    float4* __restrict__ g2, float4* __restrict__ g3,
    float* __restrict__ d_out)
{
    const int b = blockIdx.x, t = threadIdx.x;
    if (b == 8) {
        if (t < 2) d_out[t] = 0.0f;
        return;
    }
    const int i = b * 256 + t;

    // ---- global prefix over chain-0 flags: group g = t covers atoms 8t..8t+7
    const int4 f0 = ((const int4*)chain)[2 * t];
    const int4 f1 = ((const int4*)chain)[2 * t + 1];
    const int s = (f0.x == 0) + (f0.y == 0) + (f0.z == 0) + (f0.w == 0) +
                  (f1.x == 0) + (f1.y == 0) + (f1.z == 0) + (f1.w == 0);
    const int lane = t & 63, wv = t >> 6;
    int x = s;
#pragma unroll
    for (int off = 1; off < 64; off <<= 1) {
        int y = __shfl_up(x, off);
        if (lane >= off) x += y;
    }
    __shared__ int wtot[4];
    __shared__ int gpre[256];
    __shared__ float fsum[4];
    if (lane == 63) wtot[wv] = x;
    __syncthreads();
    int wbase = 0, tot = 0;
#pragma unroll
    for (int k = 0; k < 4; ++k) {
        int v = wtot[k];
        if (k < wv) wbase += v;
        tot += v;
    }
    gpre[t] = wbase + x - s;        // exclusive prefix of group t
    __syncthreads();

    const int g = i >> 3;
    int base = gpre[g];
    for (int a = (g << 3); a < i; ++a) base += (chain[a] == 0);
    const int flag = (chain[i] == 0);
    const int slot = flag ? base : tot + (i - base);

    // ---- per-atom heavy math ----
    float e[CDIM];
#pragma unroll
    for (int k = 0; k < CDIM; ++k) e[k] = embs[i * CDIM + k];
    float sfA = 0.f, sfB = 0.f, rfA = 0.f, rfB = 0.f, dfA = 0.f, dfB = 0.f;
    float dieV = 0.f, Rv = 0.f;
#pragma unroll
    for (int k = 0; k < CDIM; ++k) {
        sfA  += e[k] * sf_elec[k];
        sfB  += e[k] * sf_elec[CDIM + k];
        rfA  += e[k] * radius[k];
        rfB  += e[k] * radius[CDIM + k];
        dfA  += e[k] * depth[k];
        dfB  += e[k] * depth[CDIM + k];
        dieV += e[k] * die[k];
        Rv   += e[k] * born[k];
    }
    dieV += 1e-6f;
    Rv += 1.0f;
    const float q = qs[i];
    float es = -(1.0f - 1.0f / dieV) * q / (Rv + 1e-6f);

    const float erA = __expf(-rfA), edA = __expf(-dfA);
    const float erB = __expf(-rfB), edB = __expf(-dfB);
    const float w0j = sqrtf(w0[i] * w0[i] + 1e-6f);

    g0[slot] = make_float4(X[i * 3 + 0], X[i * 3 + 1], X[i * 3 + 2], q);
    g1[slot] = make_float4(sfA, erA, edA, w0j);
    g2[slot] = make_float4(2.0f * s0[i], Ps[i * 3 + 0], Ps[i * 3 + 1], Ps[i * 3 + 2]);
    g3[slot] = make_float4(sfB, erB, edB, 0.0f);

    // ---- E_self partial -> wsf[b] ----
#pragma unroll
    for (int off = 32; off > 0; off >>= 1) es += __shfl_down(es, off);
    if (lane == 0) fsum[wv] = es;
    __syncthreads();
    if (t == 0) {
        wsf[b] = fsum[0] + fsum[1] + fsum[2] + fsum[3];
        if (b == 0) wsi[0] = tot;
    }
}

// ------- kernel 2: opposite-chain pair pass, LDS-staged j-side --------------
__global__ __launch_bounds__(512) void pair_kernel(
    const int* __restrict__ cnt,
    const float4* __restrict__ g0, const float4* __restrict__ g1,
    const float4* __restrict__ g2, const float4* __restrict__ g3,
    const float* __restrict__ sf_elec,
    const float* __restrict__ wsf,
    float* __restrict__ d_out)
{
    const int b = blockIdx.x, tid = threadIdx.x;

    if (b == PAIR_GRID - 1) {           // E_solv finalizer (pre completed)
        if (tid == 0) {
            float tt = 0.f;
#pragma unroll
            for (int k = 0; k < 8; ++k) tt += wsf[k];
            d_out[2] = CONVF * 0.01f * tt;
        }
        return;
    }

    const int n0 = cnt[0];
    const int B0 = (n0 + PTI - 1) / PTI;
    const int n1 = NA - n0;
    const int B1 = (n1 + PTI - 1) / PTI;
    if (b >= B0 + B1) return;

    int rbase, rend, jbeg, jend;
    if (b < B0) { rbase = b * PTI;             rend = n0; jbeg = n0; jend = NA; }
    else        { rbase = n0 + (b - B0) * PTI; rend = NA; jbeg = 0;  jend = n0; }

    const float f16 = sf_elec[2 * CDIM];

    __shared__ float4 sa[CH];
    __shared__ float4 sb[CH];
    __shared__ float  sc[CH];
    __shared__ float4 sps[PTI];
    __shared__ float se[8], sv[8];

    float xi[PTI], yi[PTI], zi[PTI], qi[PTI], sfB[PTI], erB[PTI], edB[PTI], val[PTI];
    bool hasPs = false;
#pragma unroll
    for (int t = 0; t < PTI; ++t) {
        int r = rbase + t;
        val[t] = (r < rend) ? 1.0f : 0.0f;
        r = max(min(r, rend - 1), 0);
        const float4 p0 = g0[r], p3 = g3[r], p2 = g2[r];
        xi[t] = p0.x; yi[t] = p0.y; zi[t] = p0.z; qi[t] = p0.w;
        sfB[t] = p3.x; erB[t] = p3.y; edB[t] = p3.z;
        hasPs = hasPs || (p2.y != 0.0f) || (p2.z != 0.0f) || (p2.w != 0.0f);
        if (tid == 0) sps[t] = p2;      // for the (never-taken here) Ps path
    }

    float acc_e[PTI], acc_v[PTI];
#pragma unroll
    for (int t = 0; t < PTI; ++t) { acc_e[t] = 0.f; acc_v[t] = 0.f; }

    const float* g2f = (const float*)g2;

    for (int jc = jbeg; jc < jend; jc += CH) {
        const int nc = min(CH, jend - jc);
        __syncthreads();
        for (int k = tid; k < nc; k += PTHREADS) {
            sa[k] = g0[jc + k];
            sb[k] = g1[jc + k];
            sc[k] = g2f[4 * (jc + k)];
        }
        __syncthreads();

        if (!hasPs) {
            // ---------------- fast path (Ps == 0) ----------------
            for (int jo = tid; jo < nc; jo += PTHREADS) {
                const float4 A = sa[jo];
                const float4 B = sb[jo];
                const float  S = sc[jo];
#pragma unroll
                for (int t = 0; t < PTI; ++t) {
                    const float dx = A.x - xi[t], dy = A.y - yi[t], dz = A.z - zi[t];
                    const float d2 = dx * dx + dy * dy + dz * dz + 3e-6f;
                    const float D = sqrtf(d2);
                    const float invD = __builtin_amdgcn_rcpf(D + 1e-6f);

                    const float sf = B.x + sfB[t] + invD * f16;
                    acc_e[t] += qi[t] * A.w * invD * sf;

                    const float sig_r = __builtin_amdgcn_rcpf(fmaf(B.y, erB[t], 1.0f));
                    const float s = S * fmaf(0.8f, sig_r, 0.4f);
                    const float Dm = D - s;
                    const float Dm2 = Dm * Dm;
                    const float t1 = __expf(-Dm2);
                    const float ta = t1 * __expf(fmaf(0.6f, Dm, -0.09f));
                    const float t2 = t1 * t1;
                    const float t3 = t2 * t1;
                    const float t4 = t2 * t2;
                    const float t8 = t4 * t4;
                    const float t10 = t8 * t2;
                    const float attr = ta + t3 + t10;
                    const float sig_d = __builtin_amdgcn_rcpf(fmaf(B.z, edB[t], 1.0f));
                    const float w = B.w * (sig_d + 0.5f);
                    const float repl = 5.0f * __expf(-0.3f * D * d2);
                    acc_v[t] += repl - w * attr * (1.0f / 3.0f);
                }
            }
        } else {
            // ---------------- general path (Ps != 0) ----------------
            for (int jo = tid; jo < nc; jo += PTHREADS) {
                const float4 A = sa[jo];
                const float4 B = sb[jo];
                const float  S = sc[jo];
                const float4 Pj = g2[jc + jo];
#pragma unroll
                for (int t = 0; t < PTI; ++t) {
                    const float dx = A.x - xi[t], dy = A.y - yi[t], dz = A.z - zi[t];
                    const float d2 = dx * dx + dy * dy + dz * dz + 3e-6f;
                    const float D = sqrtf(d2);
                    const float invD = __builtin_amdgcn_rcpf(D + 1e-6f);

                    const float sf = B.x + sfB[t] + invD * f16;
                    float ee = qi[t] * A.w * invD * sf;
                    const float4 Pi = sps[t];
                    const float vpx = dx + 1e-6f, vpy = dy + 1e-6f, vpz = dz + 1e-6f;
                    float vn = sqrtf(vpx * vpx + vpy * vpy + vpz * vpz);
                    vn = fmaxf(vn, 1e-12f);
                    const float OqP = (vpx * Pi.y + vpy * Pi.z + vpz * Pi.w) *
                                      __builtin_amdgcn_rcpf(vn);
                    const float OPP = Pi.y * Pj.y + Pi.z * Pj.z + Pi.w * Pj.w;
                    const float invD2 = invD * invD;
                    const float invD4 = invD2 * invD2;
                    const float invD6 = invD4 * invD2;
                    ee += OqP * invD4 + OPP * invD6;
                    acc_e[t] += ee;

                    const float sig_r = __builtin_amdgcn_rcpf(fmaf(B.y, erB[t], 1.0f));
                    const float s = S * fmaf(0.8f, sig_r, 0.4f);
                    const float Dm = D - s;
                    const float Dm2 = Dm * Dm;
                    const float t1 = __expf(-Dm2);
                    const float ta = t1 * __expf(fmaf(0.6f, Dm, -0.09f));
                    const float t2 = t1 * t1;
                    const float t3 = t2 * t1;
                    const float t4 = t2 * t2;
                    const float t8 = t4 * t4;
                    const float t10 = t8 * t2;
                    const float attr = ta + t3 + t10;
                    const float sig_d = __builtin_amdgcn_rcpf(fmaf(B.z, edB[t], 1.0f));
                    const float w = B.w * (sig_d + 0.5f);
                    const float repl = 5.0f * __expf(-0.3f * D * d2);
                    acc_v[t] += repl - w * attr * (1.0f / 3.0f);
                }
            }
        }
    }

    float ae = 0.f, av = 0.f;
#pragma unroll
    for (int t = 0; t < PTI; ++t) {
        ae += val[t] * acc_e[t];
        av += val[t] * acc_v[t];
    }
#pragma unroll
    for (int off = 32; off > 0; off >>= 1) {
        ae += __shfl_down(ae, off);
        av += __shfl_down(av, off);
    }
    const int lane = tid & 63, wid = tid >> 6;
    if (lane == 0) { se[wid] = ae; sv[wid] = av; }
    __syncthreads();
    if (tid == 0) {
        float te = 0.f, tv = 0.f;
#pragma unroll
        for (int k = 0; k < 8; ++k) { te += se[k]; tv += sv[k]; }
        atomicAdd(d_out + 1, 0.5f * CONVF * te);
        atomicAdd(d_out + 0, tv);
    }
}

extern "C" void kernel_launch(void* const* d_in, const int* in_sizes, int n_in,
                              void* d_out, int out_size, void* d_ws, size_t ws_size,
                              hipStream_t stream) {
    const float* X       = (const float*)d_in[0];
    const float* embs    = (const float*)d_in[1];
    const float* qs      = (const float*)d_in[2];
    const float* Ps      = (const float*)d_in[3];
    const float* w0      = (const float*)d_in[4];
    const float* s0      = (const float*)d_in[5];
    const int*   chain   = (const int*)d_in[6];
    const float* sf_elec = (const float*)d_in[7];
    const float* born    = (const float*)d_in[8];
    const float* die     = (const float*)d_in[9];
    const float* depth   = (const float*)d_in[10];
    const float* radius  = (const float*)d_in[11];
    float* out = (float*)d_out;

    int*   wsi = (int*)d_ws;
    float* wsf = (float*)((char*)d_ws + 64);
    float4* g0 = (float4*)((char*)d_ws + 128);
    float4* g1 = g0 + NA;
    float4* g2 = g1 + NA;
    float4* g3 = g2 + NA;

    pre_kernel<<<9, 256, 0, stream>>>(
        X, embs, qs, Ps, w0, s0, chain, sf_elec, born, die, depth, radius,
        wsi, wsf, g0, g1, g2, g3, out);
    pair_kernel<<<PAIR_GRID, PTHREADS, 0, stream>>>(
        wsi, g0, g1, g2, g3, sf_elec, wsf, out);
}